// Round 12
// baseline (317.415 us; speedup 1.0000x reference)
//
#include <hip/hip_runtime.h>
#include <hip/hip_bf16.h>
#include <stdint.h>

typedef int int4v __attribute__((ext_vector_type(4)));
typedef int int16v __attribute__((ext_vector_type(16)));
typedef float float4v __attribute__((ext_vector_type(4)));

#define KDIM 4096
#define TDIM 11008
#define BDIM 4096
#define GDIM 32

// ---------- kernel 0: per-column weight scale ----------
__global__ __launch_bounds__(256) void dwt_k(const float* __restrict__ scales,
                                             const float* __restrict__ zeros,
                                             float* __restrict__ dwt,
                                             float* __restrict__ dwtinv) {
  int t = blockIdx.x * 256 + threadIdx.x;
  float m = 1e-20f;
#pragma unroll 4
  for (int g = 0; g < GDIM; ++g) {
    float s = scales[(size_t)g * TDIM + t];
    float z = zeros[(size_t)g * TDIM + t];
    m = fmaxf(m, s * fmaxf(z, 15.0f - z));
  }
  dwt[t] = m * (1.0f / 127.0f);
  dwtinv[t] = 127.0f / m;
}

// ---------- kernel 1: fused prep ----------
// blocks [0,5504): dequant int4 -> int8 wq[T][K] (row-major, for LDS staging)
// blocks [5504,9600): x -> int8 FRAGMENT-TILED xqt[mt32][kt32][lane][16B]:
//   element (row b, k) -> mt=b>>5, kt=k>>5, lane=(b&31)+((k>>4)&1)*32, byte k&15
//   (identical to the R8/R9-validated MFMA A-operand LDS mapping)
__global__ __launch_bounds__(256) void prep_k(const unsigned* __restrict__ qw,
                                              const float* __restrict__ scales,
                                              const float* __restrict__ zeros,
                                              const float* __restrict__ dwtinv,
                                              const float* __restrict__ x,
                                              char* __restrict__ wq,
                                              char* __restrict__ xqt,
                                              float* __restrict__ dxr) {
  if (blockIdx.x < 5504) {
    int idx = blockIdx.x * 256 + threadIdx.x;
    int rb = idx / TDIM;
    int t = idx - rb * TDIM;
    int r0 = rb * 4, g = rb >> 2;
    float s = scales[(size_t)g * TDIM + t];
    float z = zeros[(size_t)g * TDIM + t];
    float inv = dwtinv[t];
    float si = s * inv;
    float zi = -z * si;
    int w[8];
#pragma unroll
    for (int c = 0; c < 4; ++c) {
      unsigned q = qw[(size_t)(r0 + c) * TDIM + t];
      unsigned lo = 0, hi = 0;
#pragma unroll
      for (int i = 0; i < 4; ++i) {
        int iv = (int)rintf(fmaf((float)((q >> (4 * i)) & 0xFu), si, zi));
        lo |= (unsigned)(iv & 0xFF) << (8 * i);
      }
#pragma unroll
      for (int i = 4; i < 8; ++i) {
        int iv = (int)rintf(fmaf((float)((q >> (4 * i)) & 0xFu), si, zi));
        hi |= (unsigned)(iv & 0xFF) << (8 * (i - 4));
      }
      w[2 * c] = (int)lo;
      w[2 * c + 1] = (int)hi;
    }
    int4v v0 = {w[0], w[1], w[2], w[3]};
    int4v v1 = {w[4], w[5], w[6], w[7]};
    char* dst = wq + (size_t)t * KDIM + rb * 32;
    *(int4v*)dst = v0;
    *(int4v*)(dst + 16) = v1;
  } else {
    const int b = blockIdx.x - 5504;  // row 0..4095
    const int tid = threadIdx.x;      // covers k in [tid*16, tid*16+16)
    const float* row = x + (size_t)b * KDIM + tid * 16;
    float4v v[4];
    float m = 0.0f;
#pragma unroll
    for (int j = 0; j < 4; ++j) {
      v[j] = *(const float4v*)(row + j * 4);
#pragma unroll
      for (int i = 0; i < 4; ++i) m = fmaxf(m, fabsf(v[j][i]));
    }
#pragma unroll
    for (int off = 1; off < 64; off <<= 1) m = fmaxf(m, __shfl_xor(m, off));
    __shared__ float sm[4];
    if ((tid & 63) == 0) sm[tid >> 6] = m;
    __syncthreads();
    float rm = fmaxf(fmaxf(sm[0], sm[1]), fmaxf(sm[2], sm[3]));
    rm = fmaxf(rm, 1e-20f);
    if (tid == 0) dxr[b] = rm * (1.0f / 127.0f);
    float inv = 127.0f / rm;
    int4v p;
#pragma unroll
    for (int j = 0; j < 4; ++j) {
      unsigned w = 0;
#pragma unroll
      for (int i = 0; i < 4; ++i) {
        int iv = (int)rintf(v[j][i] * inv);
        w |= (unsigned)(iv & 0xFF) << (8 * i);
      }
      p[j] = (int)w;
    }
    *(int4v*)(xqt + (((size_t)(b >> 5) * 128 + (tid >> 1)) << 10) +
              (((b & 31) + (tid & 1) * 32) << 4)) = p;
  }
}

// ---------- kernel 2: 256x256 i8 GEMM — A direct-from-global (tiled), B in LDS ----------
// Per tile T (1 barrier): vmcnt(8)[retire stB(T+1), keep A(T)] -> BARR -> stage
// stB(T+2)->buf[T&1] (write-window: buf's reads issued at T-1, >=1 MFMA cluster +
// barrier before write lands; x3-validated) -> issue A(T+1) 8x coalesced 1KB loads
// -> read bv(T+1) from buf^1 (4 ds_read) -> MFMA(T) on regs (compiler auto-emits
// counted vmcnt/lgkm for reg deps; next-tile loads drain UNDER the MFMA cluster).
static __device__ __forceinline__ void gload16(const void* g, void* l) {
  __builtin_amdgcn_global_load_lds(
      (const __attribute__((address_space(1))) unsigned*)g,
      (__attribute__((address_space(3))) unsigned*)l, 16, 0, 0);
}

#define BARR() __builtin_amdgcn_s_barrier()
#define VMC8() asm volatile("s_waitcnt vmcnt(8)" ::: "memory")
#define VMC10() asm volatile("s_waitcnt vmcnt(10)" ::: "memory")
#define SB0() __builtin_amdgcn_sched_barrier(0)

__global__ __launch_bounds__(512, 2) void gemmq4_k(const char* __restrict__ xqt,
                                                   const char* __restrict__ wq,
                                                   const float* __restrict__ dxr,
                                                   const float* __restrict__ dwt,
                                                   const float* __restrict__ bias,
                                                   float* __restrict__ out) {
  __shared__ char sB[2 * 256 * 64];  // 32 KiB: [buf][256 rows][64K] i8 (R9-verbatim)
  const int tid = threadIdx.x;
  const int lane = tid & 63;
  const int wid = tid >> 6;
  const int wm = wid >> 2, wn = wid & 3;  // 2M x 4N waves, wave out 128x64

  // XCD swizzle: nwg = 16*43 = 688 = 8*86 (per XCD: 2 mb values x all nb)
  const int bid = blockIdx.x;
  const int swzb = (bid & 7) * 86 + (bid >> 3);
  const int mb = swzb / 43, nb = swzb % 43;
  const int m0 = mb * 256, n0 = nb * 256;

  // ---- B staging (R9-verbatim, validated conflict-free) ----
  const int srow = tid >> 2;  // 0..127
  const int spc = tid & 3;
  const int skb = spc ^ (srow & 3) ^ ((srow >> 2) & 3);
  const char* gB = wq + (size_t)(n0 + srow) * KDIM + skb * 16;
  auto stB = [&](int b, int kt) {
    gload16(gB + kt * 64, sB + b * 16384 + tid * 16);
    gload16(gB + (size_t)128 * KDIM + kt * 64, sB + b * 16384 + tid * 16 + 8192);
  };

  // ---- B read addressing (R9-verbatim) ----
  const int l31 = lane & 31, hi5 = lane >> 5;
  const int rsw = (l31 & 3) ^ ((l31 >> 2) & 3);
  const int pc0 = (hi5 ^ rsw) * 16;
  const int pc1 = ((hi5 ^ rsw) ^ 2) * 16;
  const char* bRd = sB + (wn * 64 + l31) * 64;

  // ---- A direct-global addressing: frag (mtile, ktile) at contiguous 1KB ----
  const char* pA = xqt + (((size_t)(m0 >> 5) + wm * 4) << 17) + (lane << 4);
  // load offset: fi*131072 + (T*2+ks)*1024

  int16v acc[4][2];
#pragma unroll
  for (int i = 0; i < 4; ++i)
#pragma unroll
    for (int j = 0; j < 2; ++j) acc[i][j] = (int16v)(0);

  int4v avA[4][2], avB[4][2], bvA[2][2], bvB[2][2];

#define A_ISSUE(AV, TT)                                                       \
  _Pragma("unroll") for (int fi = 0; fi < 4; ++fi)                            \
    _Pragma("unroll") for (int ks = 0; ks < 2; ++ks)                          \
      AV[fi][ks] = *(const int4v*)(pA + fi * 131072 + ((TT) * 2 + ks) * 1024);
#define B_READS(BV, BUFN)                                                     \
  _Pragma("unroll") for (int fj = 0; fj < 2; ++fj) {                          \
    BV[fj][0] = *(const int4v*)(bRd + (BUFN) * 16384 + fj * 2048 + pc0);      \
    BV[fj][1] = *(const int4v*)(bRd + (BUFN) * 16384 + fj * 2048 + pc1);      \
  }
#define MFMA16(AV, BV)                                                        \
  __builtin_amdgcn_s_setprio(1);                                              \
  _Pragma("unroll") for (int fi = 0; fi < 4; ++fi)                            \
    _Pragma("unroll") for (int fj = 0; fj < 2; ++fj) {                        \
      int16v c = acc[fi][fj];                                                 \
      c = __builtin_amdgcn_mfma_i32_32x32x32_i8(AV[fi][0], BV[fj][0], c, 0, 0, 0); \
      c = __builtin_amdgcn_mfma_i32_32x32x32_i8(AV[fi][1], BV[fj][1], c, 0, 0, 0); \
      acc[fi][fj] = c;                                                        \
    }                                                                         \
  __builtin_amdgcn_s_setprio(0)

#define TILE(BUF, TT, AVc, AVn, BVc, BVn)                                     \
  {                                                                           \
    VMC8(); SB0();       /* retire stB(T+1); A(T) stays in flight */          \
    BARR();              /* buf^1 now fully written; stage window opens */    \
    stB(BUF, ((TT) + 2) & 63); SB0();                                         \
    A_ISSUE(AVn, ((TT) + 1) & 63);                                            \
    B_READS(BVn, (BUF) ^ 1); SB0();                                           \
    MFMA16(AVc, BVc);                                                         \
  }

  // prologue: stB(0)->buf0, stB(1)->buf1, A(0); retire stB(0); bv(0)
  stB(0, 0);
  stB(1, 1);
  A_ISSUE(avA, 0);
  VMC10();  // outstanding: stB1(2)+A0(8); stB0 retired
  BARR();
  B_READS(bvA, 0);

  for (int u = 0; u < 32; ++u) {
    TILE(0, 2 * u, avA, avB, bvA, bvB);
    TILE(1, 2 * u + 1, avB, avA, bvB, bvA);
  }

  // epilogue: C layout (32x32): col = lane&31, row = (e&3) + 8*(e>>2) + 4*(lane>>5)
  const int colb = n0 + wn * 64 + l31;
  const int rowb = m0 + wm * 128 + 4 * hi5;
#pragma unroll
  for (int fi = 0; fi < 4; ++fi) {
#pragma unroll
    for (int fj = 0; fj < 2; ++fj) {
      const int col = colb + fj * 32;
      const float dw = dwt[col];
      const float bs = bias[col];
      int16v c = acc[fi][fj];
#pragma unroll
      for (int e = 0; e < 16; ++e) {
        const int row = rowb + fi * 32 + (e & 3) + 8 * (e >> 2);
        out[(size_t)row * TDIM + col] = (float)c[e] * dw * dxr[row] + bs;
      }
    }
  }
}

extern "C" void kernel_launch(void* const* d_in, const int* in_sizes, int n_in,
                              void* d_out, int out_size, void* d_ws, size_t ws_size,
                              hipStream_t stream) {
  const float* x = (const float*)d_in[0];
  const unsigned* qw = (const unsigned*)d_in[1];
  const float* scales = (const float*)d_in[2];
  const float* zeros = (const float*)d_in[3];
  const float* bias = (const float*)d_in[4];
  float* out = (float*)d_out;

  char* ws = (char*)d_ws;
  char* wq = ws;                                   // [TDIM][KDIM] i8, 45.1MB
  char* xqt = ws + (size_t)TDIM * KDIM;            // fragment-tiled x, 16.8MB
  float* dwt = (float*)(ws + (size_t)TDIM * KDIM + (size_t)BDIM * KDIM);
  float* dwtinv = dwt + TDIM;
  float* dxr = dwtinv + TDIM;

  dwt_k<<<43, 256, 0, stream>>>(scales, zeros, dwt, dwtinv);
  prep_k<<<9600, 256, 0, stream>>>(qw, scales, zeros, dwtinv, x, wq, xqt, dxr);
  gemmq4_k<<<688, 512, 0, stream>>>(xqt, wq, dxr, dwt, bias, out);
}

// Round 13
// 263.476 us; speedup vs baseline: 1.2047x; 1.2047x over previous
//
#include <hip/hip_runtime.h>
#include <hip/hip_bf16.h>
#include <stdint.h>

typedef int int4v __attribute__((ext_vector_type(4)));
typedef int int16v __attribute__((ext_vector_type(16)));
typedef float float4v __attribute__((ext_vector_type(4)));

#define KDIM 4096
#define TDIM 11008
#define BDIM 4096
#define GDIM 32

// ---------- kernel 0: per-column weight scale  dwt[t] = max_g s*max(z,15-z) / 127 ----------
__global__ __launch_bounds__(256) void dwt_k(const float* __restrict__ scales,
                                             const float* __restrict__ zeros,
                                             float* __restrict__ dwt,
                                             float* __restrict__ dwtinv) {
  int t = blockIdx.x * 256 + threadIdx.x;  // 43*256 = 11008 exact
  float m = 1e-20f;
#pragma unroll 4
  for (int g = 0; g < GDIM; ++g) {
    float s = scales[(size_t)g * TDIM + t];
    float z = zeros[(size_t)g * TDIM + t];
    m = fmaxf(m, s * fmaxf(z, 15.0f - z));
  }
  dwt[t] = m * (1.0f / 127.0f);
  dwtinv[t] = 127.0f / m;
}

// ---------- kernel 1: fused prep — blocks [0,5504): dequant int4->int8 wq[T][K];
//                      blocks [5504,9600): per-row x quant (row-major xq) ----------
__global__ __launch_bounds__(256) void prep_k(const unsigned* __restrict__ qw,
                                              const float* __restrict__ scales,
                                              const float* __restrict__ zeros,
                                              const float* __restrict__ dwtinv,
                                              const float* __restrict__ x,
                                              char* __restrict__ wq,
                                              char* __restrict__ xq,
                                              float* __restrict__ dxr) {
  if (blockIdx.x < 5504) {
    int idx = blockIdx.x * 256 + threadIdx.x;  // 128*TDIM exact
    int rb = idx / TDIM;
    int t = idx - rb * TDIM;
    int r0 = rb * 4, g = rb >> 2;
    float s = scales[(size_t)g * TDIM + t];
    float z = zeros[(size_t)g * TDIM + t];
    float inv = dwtinv[t];
    float si = s * inv;
    float zi = -z * si;
    int w[8];
#pragma unroll
    for (int c = 0; c < 4; ++c) {
      unsigned q = qw[(size_t)(r0 + c) * TDIM + t];
      unsigned lo = 0, hi = 0;
#pragma unroll
      for (int i = 0; i < 4; ++i) {
        int iv = (int)rintf(fmaf((float)((q >> (4 * i)) & 0xFu), si, zi));
        lo |= (unsigned)(iv & 0xFF) << (8 * i);
      }
#pragma unroll
      for (int i = 4; i < 8; ++i) {
        int iv = (int)rintf(fmaf((float)((q >> (4 * i)) & 0xFu), si, zi));
        hi |= (unsigned)(iv & 0xFF) << (8 * (i - 4));
      }
      w[2 * c] = (int)lo;
      w[2 * c + 1] = (int)hi;
    }
    int4v v0 = {w[0], w[1], w[2], w[3]};
    int4v v1 = {w[4], w[5], w[6], w[7]};
    char* dst = wq + (size_t)t * KDIM + rb * 32;
    *(int4v*)dst = v0;
    *(int4v*)(dst + 16) = v1;
  } else {
    const int b = blockIdx.x - 5504;  // 4096 rows
    const int tid = threadIdx.x;
    const float* row = x + (size_t)b * KDIM;
    float4v v[4];
    float m = 0.0f;
#pragma unroll
    for (int j = 0; j < 4; ++j) {
      v[j] = *(const float4v*)(row + (tid + 256 * j) * 4);
#pragma unroll
      for (int i = 0; i < 4; ++i) m = fmaxf(m, fabsf(v[j][i]));
    }
#pragma unroll
    for (int off = 1; off < 64; off <<= 1) m = fmaxf(m, __shfl_xor(m, off));
    __shared__ float sm[4];
    if ((tid & 63) == 0) sm[tid >> 6] = m;
    __syncthreads();
    float rm = fmaxf(fmaxf(sm[0], sm[1]), fmaxf(sm[2], sm[3]));
    rm = fmaxf(rm, 1e-20f);
    if (tid == 0) dxr[b] = rm * (1.0f / 127.0f);
    float inv = 127.0f / rm;
#pragma unroll
    for (int j = 0; j < 4; ++j) {
      unsigned w = 0;
#pragma unroll
      for (int i = 0; i < 4; ++i) {
        int iv = (int)rintf(v[j][i] * inv);
        w |= (unsigned)(iv & 0xFF) << (8 * i);
      }
      *(unsigned*)(xq + (size_t)b * KDIM + (tid + 256 * j) * 4) = w;
    }
  }
}

// ---------- kernel 2: 256x256 i8 GEMM, split-lgkmcnt overlapped phase (R9 verbatim) ----------
static __device__ __forceinline__ void gload16(const void* g, void* l) {
  __builtin_amdgcn_global_load_lds(
      (const __attribute__((address_space(1))) unsigned*)g,
      (__attribute__((address_space(3))) unsigned*)l, 16, 0, 0);
}

#define BARR() __builtin_amdgcn_s_barrier()
#define LGKM0() asm volatile("s_waitcnt lgkmcnt(0)" ::: "memory")
#define LGKM6() asm volatile("s_waitcnt lgkmcnt(6)" ::: "memory")
#define VMC4() asm volatile("s_waitcnt vmcnt(4)" ::: "memory")
#define SB0() __builtin_amdgcn_sched_barrier(0)

__global__ __launch_bounds__(512, 2) void gemmq_k(const char* __restrict__ xq,
                                                  const char* __restrict__ wq,
                                                  const float* __restrict__ dxr,
                                                  const float* __restrict__ dwt,
                                                  const float* __restrict__ bias,
                                                  float* __restrict__ out) {
  __shared__ char sA[2 * 256 * 64];  // 32 KiB: [buf][row][64K] i8, 64B rows
  __shared__ char sB[2 * 256 * 64];  // 32 KiB
  const int tid = threadIdx.x;
  const int lane = tid & 63;
  const int wid = tid >> 6;
  const int wm = wid >> 2, wn = wid & 3;  // 2M x 4N waves; wave out 128x64

  // XCD swizzle: nwg = 16*43 = 688 = 8*86
  const int bid = blockIdx.x;
  const int swzb = (bid & 7) * 86 + (bid >> 3);
  const int mb = swzb / 43, nb = swzb % 43;
  const int m0 = mb * 256, n0 = nb * 256;

  // staging: chunk ci in {tid, tid+512}; row = ci>>2 (r, r+128), pc = tid&3
  const int srow = tid >> 2;  // 0..127
  const int spc = tid & 3;
  const int skb = spc ^ (srow & 3) ^ ((srow >> 2) & 3);
  const char* gA = xq + (size_t)(m0 + srow) * KDIM + skb * 16;
  const char* gB = wq + (size_t)(n0 + srow) * KDIM + skb * 16;
  const int d0 = tid * 16, d1 = tid * 16 + 8192;

  auto stA = [&](int b, int kt) {
    gload16(gA + kt * 64, sA + b * 16384 + d0);
    gload16(gA + (size_t)128 * KDIM + kt * 64, sA + b * 16384 + d1);
  };
  auto stB = [&](int b, int kt) {
    gload16(gB + kt * 64, sB + b * 16384 + d0);
    gload16(gB + (size_t)128 * KDIM + kt * 64, sB + b * 16384 + d1);
  };

  // read addressing
  const int l31 = lane & 31, hi5 = lane >> 5;
  const int swz = (l31 & 3) ^ ((l31 >> 2) & 3);
  const int pc0 = ((hi5 ^ swz)) * 16;        // ks=0
  const int pc1 = ((hi5 ^ swz) ^ 2) * 16;    // ks=1
  const char* aRd = sA + (wm * 128 + l31) * 64;
  const char* bRd = sB + (wn * 64 + l31) * 64;

  int16v acc[4][2];
#pragma unroll
  for (int i = 0; i < 4; ++i)
#pragma unroll
    for (int j = 0; j < 2; ++j) acc[i][j] = (int16v)(0);

#define TILEQ(BUF, TT)                                                        \
  {                                                                           \
    const char* ap = aRd + (BUF) * 16384;                                     \
    const char* bp = bRd + (BUF) * 16384;                                     \
    int4v av[4][2], bv[2][2];                                                 \
    /* issue ks0 group first (6 reads), then ks1 (6): in-order completion */  \
    _Pragma("unroll") for (int fi = 0; fi < 4; ++fi)                          \
      av[fi][0] = *(const int4v*)(ap + fi * 2048 + pc0);                      \
    _Pragma("unroll") for (int fj = 0; fj < 2; ++fj)                          \
      bv[fj][0] = *(const int4v*)(bp + fj * 2048 + pc0);                      \
    _Pragma("unroll") for (int fi = 0; fi < 4; ++fi)                          \
      av[fi][1] = *(const int4v*)(ap + fi * 2048 + pc1);                      \
    _Pragma("unroll") for (int fj = 0; fj < 2; ++fj)                          \
      bv[fj][1] = *(const int4v*)(bp + fj * 2048 + pc1);                      \
    SB0();                                                                    \
    BARR();                                                                   \
    LGKM6(); SB0();                                                           \
    __builtin_amdgcn_s_setprio(1);                                            \
    _Pragma("unroll") for (int fi = 0; fi < 4; ++fi)                          \
      _Pragma("unroll") for (int fj = 0; fj < 2; ++fj)                        \
        acc[fi][fj] = __builtin_amdgcn_mfma_i32_32x32x32_i8(av[fi][0], bv[fj][0], acc[fi][fj], 0, 0, 0); \
    __builtin_amdgcn_s_setprio(0);                                            \
    LGKM0(); SB0();                                                           \
    const int kn = ((TT) + 2) & 63;                                           \
    stA(BUF, kn); stB(BUF, kn);                                               \
    SB0();                                                                    \
    __builtin_amdgcn_s_setprio(1);                                            \
    _Pragma("unroll") for (int fi = 0; fi < 4; ++fi)                          \
      _Pragma("unroll") for (int fj = 0; fj < 2; ++fj)                        \
        acc[fi][fj] = __builtin_amdgcn_mfma_i32_32x32x32_i8(av[fi][1], bv[fj][1], acc[fi][fj], 0, 0, 0); \
    __builtin_amdgcn_s_setprio(0);                                            \
    VMC4(); BARR();                                                           \
  }

  // prologue: stage tiles 0,1 (8 loads); vmcnt(4) -> tile0 landed
  stA(0, 0); stB(0, 0);
  stA(1, 1); stB(1, 1);
  VMC4();
  BARR();

  for (int u = 0; u < 32; ++u) {
    TILEQ(0, 2 * u);
    TILEQ(1, 2 * u + 1);
  }

  // epilogue: C layout (32x32): col = lane&31, row = (e&3) + 8*(e>>2) + 4*(lane>>5)
  const int colb = n0 + wn * 64 + l31;
  const int rowb = m0 + wm * 128 + 4 * hi5;
#pragma unroll
  for (int fi = 0; fi < 4; ++fi) {
#pragma unroll
    for (int fj = 0; fj < 2; ++fj) {
      const int col = colb + fj * 32;
      const float dw = dwt[col];
      const float bs = bias[col];
      int16v c = acc[fi][fj];
#pragma unroll
      for (int e = 0; e < 16; ++e) {
        const int row = rowb + fi * 32 + (e & 3) + 8 * (e >> 2);
        out[(size_t)row * TDIM + col] = (float)c[e] * dw * dxr[row] + bs;
      }
    }
  }
}

extern "C" void kernel_launch(void* const* d_in, const int* in_sizes, int n_in,
                              void* d_out, int out_size, void* d_ws, size_t ws_size,
                              hipStream_t stream) {
  const float* x = (const float*)d_in[0];
  const unsigned* qw = (const unsigned*)d_in[1];
  const float* scales = (const float*)d_in[2];
  const float* zeros = (const float*)d_in[3];
  const float* bias = (const float*)d_in[4];
  float* out = (float*)d_out;

  char* ws = (char*)d_ws;
  char* wq = ws;                                   // [TDIM][KDIM] i8, 45.1MB
  char* xq = ws + (size_t)TDIM * KDIM;             // [BDIM][KDIM] i8, 16.8MB
  float* dwt = (float*)(ws + (size_t)TDIM * KDIM + (size_t)BDIM * KDIM);
  float* dwtinv = dwt + TDIM;
  float* dxr = dwtinv + TDIM;

  dwt_k<<<43, 256, 0, stream>>>(scales, zeros, dwt, dwtinv);
  prep_k<<<9600, 256, 0, stream>>>(qw, scales, zeros, dwtinv, x, wq, xq, dxr);
  gemmq_k<<<688, 512, 0, stream>>>(xq, wq, dxr, dwt, bias, out);
}